// Round 15
// baseline (235.579 us; speedup 1.0000x reference)
//
#include <hip/hip_runtime.h>
#include <hip/hip_bf16.h>

#define B_SZ   2
#define H_SZ   48
#define W_SZ   48
#define L_SZ   2304          // H*W
#define CIN    768           // C_INNER
#define KG     4
#define DI     192           // D_IN (channels per direction)
#define NS     16            // N_STATE
#define RR     12            // R_RANK
#define XD     44            // RR + 2*NS
#define MTOK   4608          // B*L
#define CL     32            // scan chunk length
#define NC     72            // L / CL

typedef __attribute__((ext_vector_type(8))) short short8;
typedef __attribute__((ext_vector_type(4))) float f32x4;

__device__ inline ushort f2b(float f) {
    uint u = __builtin_bit_cast(uint, f);
    u = (u + 0x7FFF + ((u >> 16) & 1)) >> 16;   // RNE to bf16
    return (ushort)u;
}
__device__ inline float b2f(ushort b) {
    uint u = ((uint)b) << 16;
    return __builtin_bit_cast(float, u);
}
__device__ inline short8 f2b8(float4 a, float4 b) {
    short8 r;
    r[0] = (short)f2b(a.x); r[1] = (short)f2b(a.y);
    r[2] = (short)f2b(a.z); r[3] = (short)f2b(a.w);
    r[4] = (short)f2b(b.x); r[5] = (short)f2b(b.y);
    r[6] = (short)f2b(b.z); r[7] = (short)f2b(b.w);
    return r;
}

// ---------------------------------------------------------------------------
// MFMA GEMM, TN=64 column tiles:  C[M,N] = A[M,K] * Bw[N,K]^T
// A bf16 (ABF) or fp32 cast inline; Bw fp32 cast inline.
// C stored fp32 (CBF=false) or bf16 (CBF=true). 4 waves stacked on M.
// ---------------------------------------------------------------------------
template<int TM, bool ABF, bool CBF>
__global__ __launch_bounds__(256) void gemm_tn64(
        const void* __restrict__ Av, const float* __restrict__ Bw,
        void* __restrict__ Cv, int M, int N, int K) {
    __shared__ ushort As[TM][40];
    __shared__ ushort Bs[64][40];
    const int tid  = threadIdx.x;
    const int lane = tid & 63;
    const int wave = tid >> 6;
    constexpr int MF = TM / 64;
    const int wrow = wave * (MF * 16);
    const int bm = blockIdx.y * TM, bn = blockIdx.x * 64;
    const int frow = lane & 15;
    const int fk   = (lane >> 4) * 8;
    const int orow = (lane >> 4) * 4;

    f32x4 acc[MF][4] = {};

    for (int k0 = 0; k0 < K; k0 += 32) {
        short8 aval[MF];
#pragma unroll
        for (int i = 0; i < MF; ++i) {
            int idx = tid + i * 256;
            int row = idx >> 2, q = idx & 3;
            if (ABF) {
                aval[i] = *(const short8*)&((const ushort*)Av)[(size_t)(bm + row) * K + k0 + q * 8];
            } else {
                const float* ap = &((const float*)Av)[(size_t)(bm + row) * K + k0 + q * 8];
                aval[i] = f2b8(*(const float4*)ap, *(const float4*)(ap + 4));
            }
        }
        const float* bp = &Bw[(size_t)(bn + (tid >> 2)) * K + k0 + (tid & 3) * 8];
        short8 bval = f2b8(*(const float4*)bp, *(const float4*)(bp + 4));

        __syncthreads();
#pragma unroll
        for (int i = 0; i < MF; ++i) {
            int idx = tid + i * 256;
            *(short8*)&As[idx >> 2][(idx & 3) * 8] = aval[i];
        }
        *(short8*)&Bs[tid >> 2][(tid & 3) * 8] = bval;
        __syncthreads();

        short8 af[MF], bf[4];
#pragma unroll
        for (int mi = 0; mi < MF; ++mi)
            af[mi] = *(const short8*)&As[wrow + mi * 16 + frow][fk];
#pragma unroll
        for (int ni = 0; ni < 4; ++ni)
            bf[ni] = *(const short8*)&Bs[ni * 16 + frow][fk];
#pragma unroll
        for (int mi = 0; mi < MF; ++mi)
#pragma unroll
            for (int ni = 0; ni < 4; ++ni)
                acc[mi][ni] = __builtin_amdgcn_mfma_f32_16x16x32_bf16(
                                  af[mi], bf[ni], acc[mi][ni], 0, 0, 0);
    }

#pragma unroll
    for (int mi = 0; mi < MF; ++mi) {
        int rbase = bm + wrow + mi * 16 + orow;
#pragma unroll
        for (int ni = 0; ni < 4; ++ni) {
            int col = bn + ni * 16 + frow;
#pragma unroll
            for (int r = 0; r < 4; ++r) {
                if (CBF)
                    ((ushort*)Cv)[(size_t)(rbase + r) * N + col] = f2b(acc[mi][ni][r]);
                else
                    ((float*)Cv)[(size_t)(rbase + r) * N + col] = acc[mi][ni][r];
            }
        }
    }
}

// ---------------------------------------------------------------------------
// Depthwise 3x3 conv (SAME) + bias + SiLU on bf16 NHWC input; scatter into
// the four scan orders xsb[b][k][l'][d] (bf16).
// ---------------------------------------------------------------------------
__global__ __launch_bounds__(256) void conv_silu_scatter(
        const ushort* __restrict__ xzb, const float* __restrict__ cw,
        const float* __restrict__ cb, ushort* __restrict__ xsb) {
    int idx = blockIdx.x * 256 + threadIdx.x;
    int c = idx % CIN;
    int rest = idx / CIN;
    int w = rest % W_SZ; rest /= W_SZ;
    int h = rest % H_SZ;
    int b = rest / H_SZ;

    float acc = cb[c];
#pragma unroll
    for (int dh = -1; dh <= 1; ++dh) {
        int hh = h + dh;
        if (hh < 0 || hh >= H_SZ) continue;
#pragma unroll
        for (int dw = -1; dw <= 1; ++dw) {
            int ww = w + dw;
            if (ww < 0 || ww >= W_SZ) continue;
            acc += b2f(xzb[(size_t)((b * H_SZ + hh) * W_SZ + ww) * CIN + c])
                 * cw[c * 9 + (dh + 1) * 3 + (dw + 1)];
        }
    }
    float s = acc / (1.f + __expf(-acc));   // SiLU

    int k = c / DI, d = c % DI;
    int lrow = h * W_SZ + w;
    int lcol = w * H_SZ + h;
    int l;
    if      (k == 0) l = lrow;
    else if (k == 1) l = lcol;
    else if (k == 2) l = L_SZ - 1 - lrow;
    else             l = L_SZ - 1 - lcol;
    xsb[(size_t)((b * KG + k) * L_SZ + l) * DI + d] = f2b(s);
}

// ---------------------------------------------------------------------------
// MFMA fused x-projection + dt-projection (768 threads = 12 waves).
// dts emitted as bf16.  (R12 version — fusion with scanA reverted.)
// ---------------------------------------------------------------------------
__global__ __launch_bounds__(768) void xproj_dt_mfma(
        const ushort* __restrict__ xsb, const float* __restrict__ xpw,
        const float* __restrict__ dtw, const float* __restrict__ dtb,
        float* __restrict__ xdbl, ushort* __restrict__ dts_b) {
    __shared__ ushort Ws[48][200];
    __shared__ ushort Wd[192][40];
    __shared__ ushort dsh[64][40];

    const int tid  = threadIdx.x;
    const int lane = tid & 63;
    const int wave = tid >> 6;        // 0..11
    const int bm = blockIdx.x * 64;
    const int bk = blockIdx.y;
    const int k  = bk & 3;
    const int frow = lane & 15;
    const int fk   = (lane >> 4) * 8;
    const int orow = (lane >> 4) * 4;
    const int rg = wave & 3;
    const int cg = wave >> 2;

#pragma unroll
    for (int i = 0; i < 3; ++i) {
        int idx = tid + i * 768;
        int row = idx / 48, g = idx % 48;
        ushort4 u = {0, 0, 0, 0};
        if (row < XD) {
            float4 v = *(const float4*)&xpw[((size_t)(k * XD) + row) * 192 + g * 4];
            u.x = f2b(v.x); u.y = f2b(v.y); u.z = f2b(v.z); u.w = f2b(v.w);
        }
        *(ushort4*)&Ws[row][g * 4] = u;
    }
#pragma unroll
    for (int i = 0; i < 2; ++i) {
        int idx = tid + i * 768;
        if (idx < 960) {
            float4 z = {0.f, 0.f, 0.f, 0.f};
            *(float4*)&Wd[idx / 5][(idx % 5) * 8] = z;
        } else if (idx < 1280) {
            int j = idx - 960;
            float4 z = {0.f, 0.f, 0.f, 0.f};
            *(float4*)&dsh[j / 5][(j % 5) * 8] = z;
        }
    }
    __syncthreads();

#pragma unroll
    for (int i = 0; i < 3; ++i) {
        int idx = tid + i * 768;
        int row = idx / RR, c = idx % RR;
        Wd[row][c] = f2b(dtw[((size_t)(k * DI) + row) * RR + c]);
    }

    f32x4 acc1 = {};
    const ushort* arow = &xsb[(size_t)(bk * L_SZ + bm + rg * 16 + frow) * DI];
#pragma unroll
    for (int k0 = 0; k0 < 192; k0 += 32) {
        short8 af = *(const short8*)&arow[k0 + fk];
        short8 bv = *(const short8*)&Ws[cg * 16 + frow][k0 + fk];
        acc1 = __builtin_amdgcn_mfma_f32_16x16x32_bf16(af, bv, acc1, 0, 0, 0);
    }

    {
        int col = cg * 16 + frow;
#pragma unroll
        for (int r = 0; r < 4; ++r) {
            float v = acc1[r];
            int row = rg * 16 + orow + r;
            if (col >= RR && col < XD)
                xdbl[(size_t)(bk * L_SZ + bm + row) * XD + col] = v;
            if (cg == 0 && col < RR)
                dsh[row][col] = f2b(v);
        }
    }
    __syncthreads();

    {
        int d = wave * 16 + frow;
        short8 bv = *(const short8*)&Wd[d][fk];
        float bias = dtb[k * DI + d];
#pragma unroll
        for (int rg2 = 0; rg2 < 4; ++rg2) {
            short8 af2 = *(const short8*)&dsh[rg2 * 16 + frow][fk];
            f32x4 a2 = {};
            a2 = __builtin_amdgcn_mfma_f32_16x16x32_bf16(af2, bv, a2, 0, 0, 0);
#pragma unroll
            for (int r = 0; r < 4; ++r) {
                float a = a2[r] + bias;
                float sp = (a > 20.f) ? a : log1pf(__expf(a));
                dts_b[(size_t)(bk * L_SZ + bm + rg2 * 16 + orow + r) * DI + d] = f2b(sp);
            }
        }
    }
}

// ---------------------------------------------------------------------------
// Scan pass A: 384 threads = (d:192, state-half:2), each thread scans CL=32
// over 8 states. No cross-half combine needed (E/S slices disjoint).
// Wave-uniform exp fast path (high half starts its e1 chain at e1^9).
// ---------------------------------------------------------------------------
__global__ __launch_bounds__(384) void scan_passA(
        const ushort* __restrict__ dts_b, const ushort* __restrict__ xsb,
        const float* __restrict__ xdbl, const float* __restrict__ A_logs,
        float* __restrict__ Ebuf, float* __restrict__ Sbuf) {
    int blk = blockIdx.x;
    int bk = blk / NC, ch = blk % NC;
    int tid = threadIdx.x;
    int d = tid % DI, half = tid / DI, nb = half * 8;
    int k = bk % KG;
    int l0 = ch * CL;

    __shared__ float bsh[CL][NS];
    for (int t = tid; t < CL * NS; t += 384) {
        int l = t / NS, n = t % NS;
        bsh[l][n] = xdbl[(size_t)(bk * L_SZ + l0 + l) * XD + RR + n];
    }
    __syncthreads();

    float Aa[8], E[8], S[8];
    const float* ar = &A_logs[(size_t)(k * DI + d) * NS + nb];
    bool fast = true;
#pragma unroll
    for (int n = 0; n < 8; ++n) {
        Aa[n] = -__expf(ar[n]);
        E[n] = 1.f; S[n] = 0.f;
        fast = fast && (fabsf(Aa[n] + (float)(nb + n + 1)) < 1e-4f * (nb + n + 1));
    }

    if (fast) {
        float P = 1.f;
#pragma unroll 4
        for (int l = 0; l < CL; ++l) {
            float dt = b2f(dts_b[(size_t)(bk * L_SZ + l0 + l) * DI + d]);
            float u  = b2f(xsb [(size_t)(bk * L_SZ + l0 + l) * DI + d]);
            float du = dt * u;
            const float* Bv = &bsh[l][nb];
            float e1 = __expf(-dt);
            P *= e1;
            float e = e1;
            if (half) { float e2 = e1 * e1, e4 = e2 * e2, e8 = e4 * e4; e = e8 * e1; }
            S[0] = fmaf(S[0], e, du * Bv[0]);
#pragma unroll
            for (int n = 1; n < 8; ++n) {
                e *= e1;
                S[n] = fmaf(S[n], e, du * Bv[n]);
            }
        }
        float Pe = P;
        if (half) { float P2 = P * P, P4 = P2 * P2, P8 = P4 * P4; Pe = P8 * P; }
        E[0] = Pe;
#pragma unroll
        for (int n = 1; n < 8; ++n) E[n] = E[n - 1] * P;
    } else {
#pragma unroll 4
        for (int l = 0; l < CL; ++l) {
            float dt = b2f(dts_b[(size_t)(bk * L_SZ + l0 + l) * DI + d]);
            float u  = b2f(xsb [(size_t)(bk * L_SZ + l0 + l) * DI + d]);
            float du = dt * u;
            const float* Bv = &bsh[l][nb];
#pragma unroll
            for (int n = 0; n < 8; ++n) {
                float e = __expf(dt * Aa[n]);
                E[n] *= e;
                S[n] = fmaf(S[n], e, du * Bv[n]);
            }
        }
    }
    float* ep = &Ebuf[(size_t)((bk * NC + ch) * DI + d) * NS + nb];
    float* sp = &Sbuf[(size_t)((bk * NC + ch) * DI + d) * NS + nb];
#pragma unroll
    for (int q = 0; q < 2; ++q) {
        *(float4*)&ep[q * 4] = make_float4(E[4*q], E[4*q+1], E[4*q+2], E[4*q+3]);
        *(float4*)&sp[q * 4] = make_float4(S[4*q], S[4*q+1], S[4*q+2], S[4*q+3]);
    }
}

// ---------------------------------------------------------------------------
// Scan pass B: chunk prefix; one thread per (bk,d,4n) -> float4 chains.
// ---------------------------------------------------------------------------
__global__ __launch_bounds__(256) void scan_passB(
        const float* __restrict__ Ebuf, const float* __restrict__ Sbuf,
        float* __restrict__ Hstart) {
    int t = blockIdx.x * 256 + threadIdx.x;       // 8*192*4 = 6144
    int bk = t / (DI * 4);
    int dn = (t % (DI * 4)) * 4;
    size_t off = (size_t)(bk * NC) * DI * NS + dn;
    const size_t stride = (size_t)DI * NS;

    float4 h = {0.f, 0.f, 0.f, 0.f};
    float4 e = *(const float4*)&Ebuf[off];
    float4 s = *(const float4*)&Sbuf[off];
    for (int c = 0; c < NC; ++c) {
        float4 en = {0.f,0.f,0.f,0.f}, sn = {0.f,0.f,0.f,0.f};
        if (c + 1 < NC) {
            en = *(const float4*)&Ebuf[off + stride];
            sn = *(const float4*)&Sbuf[off + stride];
        }
        *(float4*)&Hstart[off] = h;
        h.x = fmaf(e.x, h.x, s.x);
        h.y = fmaf(e.y, h.y, s.y);
        h.z = fmaf(e.z, h.z, s.z);
        h.w = fmaf(e.w, h.w, s.w);
        off += stride; e = en; s = sn;
    }
}

// ---------------------------------------------------------------------------
// Scan pass C: 384 threads = (d:192, state-half:2). Phase 1: replay chunk
// over 8 states, write per-(l,d) partial dot products to LDS. Phase 2: all
// 384 threads combine halves + D*u and scatter y (bf16).
// ---------------------------------------------------------------------------
__global__ __launch_bounds__(384) void scan_passC(
        const ushort* __restrict__ dts_b, const ushort* __restrict__ xsb,
        const float* __restrict__ xdbl, const float* __restrict__ A_logs,
        const float* __restrict__ Hstart, const float* __restrict__ Ds,
        ushort* __restrict__ ypre_b) {
    int blk = blockIdx.x;
    int bk = blk / NC, ch = blk % NC;
    int tid = threadIdx.x;
    int d = tid % DI, half = tid / DI, nb = half * 8;
    int k = bk % KG, b = bk / KG;
    int l0 = ch * CL;

    __shared__ float bsh[CL][NS];
    __shared__ float csh[CL][NS];
    __shared__ float psum[2][CL][DI];

    for (int t = tid; t < CL * NS; t += 384) {
        int l = t / NS, n = t % NS;
        const float* row = &xdbl[(size_t)(bk * L_SZ + l0 + l) * XD];
        bsh[l][n] = row[RR + n];
        csh[l][n] = row[RR + NS + n];
    }
    __syncthreads();

    float Aa[8], h[8];
    const float* ar = &A_logs[(size_t)(k * DI + d) * NS + nb];
    const float* hp = &Hstart[((size_t)(bk * NC + ch) * DI + d) * NS + nb];
    bool fast = true;
#pragma unroll
    for (int n = 0; n < 8; ++n) {
        Aa[n] = -__expf(ar[n]);
        h[n] = hp[n];
        fast = fast && (fabsf(Aa[n] + (float)(nb + n + 1)) < 1e-4f * (nb + n + 1));
    }

#pragma unroll 4
    for (int l = 0; l < CL; ++l) {
        float dt = b2f(dts_b[(size_t)(bk * L_SZ + l0 + l) * DI + d]);
        float u  = b2f(xsb [(size_t)(bk * L_SZ + l0 + l) * DI + d]);
        float du = dt * u;
        const float* Bv = &bsh[l][nb];
        const float* Cv = &csh[l][nb];
        float p[8];
        if (fast) {
            float e1 = __expf(-dt);
            float e = e1;
            if (half) { float e2 = e1 * e1, e4 = e2 * e2, e8 = e4 * e4; e = e8 * e1; }
            h[0] = fmaf(h[0], e, du * Bv[0]);
            p[0] = h[0] * Cv[0];
#pragma unroll
            for (int n = 1; n < 8; ++n) {
                e *= e1;
                h[n] = fmaf(h[n], e, du * Bv[n]);
                p[n] = h[n] * Cv[n];
            }
        } else {
#pragma unroll
            for (int n = 0; n < 8; ++n) {
                float e = __expf(dt * Aa[n]);
                h[n] = fmaf(h[n], e, du * Bv[n]);
                p[n] = h[n] * Cv[n];
            }
        }
        float s = ((p[0] + p[4]) + (p[1] + p[5])) + ((p[2] + p[6]) + (p[3] + p[7]));
        psum[half][l][d] = s;
    }
    __syncthreads();

    // phase 2: combine halves, add D*u, scatter. Each thread: 16 (l,d) pairs.
    float Dd = Ds[k * DI + d];
#pragma unroll
    for (int i = 0; i < 16; ++i) {
        int l = half + i * 2;
        float u = b2f(xsb[(size_t)(bk * L_SZ + l0 + l) * DI + d]);
        float y = fmaf(Dd, u, psum[0][l][d] + psum[1][l][d]);
        int lg = l0 + l;
        int pos;
        if      (k == 0) pos = lg;
        else if (k == 1) pos = (lg % H_SZ) * W_SZ + (lg / H_SZ);
        else if (k == 2) pos = L_SZ - 1 - lg;
        else { int j = L_SZ - 1 - lg; pos = (j % H_SZ) * W_SZ + (j / H_SZ); }
        ypre_b[(size_t)(b * L_SZ + pos) * CIN + k * DI + d] = f2b(y);
    }
}

// ---------------------------------------------------------------------------
// LayerNorm over CIN=768; bf16 in, bf16 out (stats in fp32).
// ---------------------------------------------------------------------------
__global__ __launch_bounds__(256) void layernorm_bf16(
        const ushort* __restrict__ y, ushort* __restrict__ yb,
        const float* __restrict__ w, const float* __restrict__ bg) {
    int wave = threadIdx.x >> 6, lane = threadIdx.x & 63;
    int tok = blockIdx.x * 4 + wave;
    const ushort* row = &y[(size_t)tok * CIN];
    ushort* rowo = &yb[(size_t)tok * CIN];
    float v[12];
    float s = 0.f;
#pragma unroll
    for (int i = 0; i < 12; ++i) { v[i] = b2f(row[lane + i * 64]); s += v[i]; }
#pragma unroll
    for (int off = 32; off >= 1; off >>= 1) s += __shfl_xor(s, off, 64);
    float mu = s * (1.f / CIN);
    float s2 = 0.f;
#pragma unroll
    for (int i = 0; i < 12; ++i) { float t = v[i] - mu; s2 += t * t; }
#pragma unroll
    for (int off = 32; off >= 1; off >>= 1) s2 += __shfl_xor(s2, off, 64);
    float rstd = rsqrtf(s2 * (1.f / CIN) + 1e-5f);
#pragma unroll
    for (int i = 0; i < 12; ++i)
        rowo[lane + i * 64] =
            f2b((v[i] - mu) * rstd * w[lane + i * 64] + bg[lane + i * 64]);
}

// ---------------------------------------------------------------------------
extern "C" void kernel_launch(void* const* d_in, const int* in_sizes, int n_in,
                              void* d_out, int out_size, void* d_ws, size_t ws_size,
                              hipStream_t stream) {
    const float* x    = (const float*)d_in[0];
    const float* inw  = (const float*)d_in[1];
    const float* cw   = (const float*)d_in[2];
    const float* cb   = (const float*)d_in[3];
    const float* xpw  = (const float*)d_in[4];
    const float* dtw  = (const float*)d_in[5];
    const float* dtb  = (const float*)d_in[6];
    const float* alog = (const float*)d_in[7];
    const float* Dsp  = (const float*)d_in[8];
    const float* lnw  = (const float*)d_in[9];
    const float* lnb  = (const float*)d_in[10];
    const float* outw = (const float*)d_in[11];
    float* out = (float*)d_out;

    float* ws = (float*)d_ws;
    const size_t SZ_BIG = (size_t)MTOK * CIN;            // 3,538,944
    const size_t SCAN_SL = (size_t)8 * NC * DI * NS;     // 1,769,472
    float* xz    = ws;                                   // bf16 in-proj out; later ypre_b
    float* xsbf  = xz  + SZ_BIG;                         // bf16 xs (float slots)
    float* dts   = xsbf + SZ_BIG / 2;                    // bf16 dts; later ynrm_b
    float* xdbl  = dts + SZ_BIG;                         // (8,L,44) fp32
    float* Ebuf  = xdbl + (size_t)8 * L_SZ * XD;
    float* Sbuf  = Ebuf + SCAN_SL;
    float* Hst   = Sbuf + SCAN_SL;
    // overlays (strictly sequential producer/consumer):
    ushort* xzb    = (ushort*)xz;     // gemm1 out (bf16) -> conv in
    ushort* xsb    = (ushort*)xsbf;   // conv -> xproj + scans
    ushort* dtsb   = (ushort*)dts;    // xproj -> scans
    ushort* ypre_b = (ushort*)xz;     // scanC out -> LN in (xzb dead after conv)
    ushort* ynrm_b = (ushort*)dts;    // LN out -> out-proj (dtsb dead after scanC)

    // 1. in-proj GEMM (bf16 MFMA, inline fp32->bf16 A-cast, bf16 C out)
    gemm_tn64<128, false, true><<<dim3(CIN / 64, MTOK / 128), 256, 0, stream>>>(
        x, inw, xzb, MTOK, CIN, 384);
    // 2. depthwise conv + SiLU + scatter (bf16 in/out)
    conv_silu_scatter<<<(B_SZ * H_SZ * W_SZ * CIN) / 256, 256, 0, stream>>>(xzb, cw, cb, xsb);
    // 3. fused MFMA x-projection + dt-projection (bf16 dts out)
    xproj_dt_mfma<<<dim3(L_SZ / 64, 8), 768, 0, stream>>>(xsb, xpw, dtw, dtb, xdbl, dtsb);
    // 4-6. chunked selective scan (CL=32; A and C use 384-thread state-half split)
    scan_passA<<<8 * NC, 384, 0, stream>>>(dtsb, xsb, xdbl, alog, Ebuf, Sbuf);
    scan_passB<<<(8 * DI * 4) / 256, 256, 0, stream>>>(Ebuf, Sbuf, Hst);
    scan_passC<<<8 * NC, 384, 0, stream>>>(dtsb, xsb, xdbl, alog, Hst, Dsp, ypre_b);
    // 7. LayerNorm: bf16 in, bf16 out
    layernorm_bf16<<<MTOK / 4, 256, 0, stream>>>(ypre_b, ynrm_b, lnw, lnb);
    // 8. out-proj GEMM (bf16 A, inline-cast B, fp32 out)
    gemm_tn64<64, true, false><<<dim3(384 / 64, MTOK / 64), 256, 0, stream>>>(
        ynrm_b, outw, out, MTOK, 384, CIN);
}

// Round 16
// 223.619 us; speedup vs baseline: 1.0535x; 1.0535x over previous
//
#include <hip/hip_runtime.h>
#include <hip/hip_bf16.h>

#define B_SZ   2
#define H_SZ   48
#define W_SZ   48
#define L_SZ   2304          // H*W
#define CIN    768           // C_INNER
#define KG     4
#define DI     192           // D_IN (channels per direction)
#define NS     16            // N_STATE
#define RR     12            // R_RANK
#define XD     44            // RR + 2*NS
#define MTOK   4608          // B*L
#define CL     32            // scan chunk length
#define NC     72            // L / CL

typedef __attribute__((ext_vector_type(8))) short short8;
typedef __attribute__((ext_vector_type(4))) float f32x4;

__device__ inline ushort f2b(float f) {
    uint u = __builtin_bit_cast(uint, f);
    u = (u + 0x7FFF + ((u >> 16) & 1)) >> 16;   // RNE to bf16
    return (ushort)u;
}
__device__ inline float b2f(ushort b) {
    uint u = ((uint)b) << 16;
    return __builtin_bit_cast(float, u);
}
__device__ inline short8 f2b8(float4 a, float4 b) {
    short8 r;
    r[0] = (short)f2b(a.x); r[1] = (short)f2b(a.y);
    r[2] = (short)f2b(a.z); r[3] = (short)f2b(a.w);
    r[4] = (short)f2b(b.x); r[5] = (short)f2b(b.y);
    r[6] = (short)f2b(b.z); r[7] = (short)f2b(b.w);
    return r;
}

// ---------------------------------------------------------------------------
// MFMA GEMM, TN=64 column tiles:  C[M,N] = A[M,K] * Bw[N,K]^T
// A bf16 (ABF) or fp32 cast inline; Bw fp32 cast inline.
// C stored fp32 (CBF=false) or bf16 (CBF=true). 4 waves stacked on M.
// ---------------------------------------------------------------------------
template<int TM, bool ABF, bool CBF>
__global__ __launch_bounds__(256) void gemm_tn64(
        const void* __restrict__ Av, const float* __restrict__ Bw,
        void* __restrict__ Cv, int M, int N, int K) {
    __shared__ ushort As[TM][40];
    __shared__ ushort Bs[64][40];
    const int tid  = threadIdx.x;
    const int lane = tid & 63;
    const int wave = tid >> 6;
    constexpr int MF = TM / 64;
    const int wrow = wave * (MF * 16);
    const int bm = blockIdx.y * TM, bn = blockIdx.x * 64;
    const int frow = lane & 15;
    const int fk   = (lane >> 4) * 8;
    const int orow = (lane >> 4) * 4;

    f32x4 acc[MF][4] = {};

    for (int k0 = 0; k0 < K; k0 += 32) {
        short8 aval[MF];
#pragma unroll
        for (int i = 0; i < MF; ++i) {
            int idx = tid + i * 256;
            int row = idx >> 2, q = idx & 3;
            if (ABF) {
                aval[i] = *(const short8*)&((const ushort*)Av)[(size_t)(bm + row) * K + k0 + q * 8];
            } else {
                const float* ap = &((const float*)Av)[(size_t)(bm + row) * K + k0 + q * 8];
                aval[i] = f2b8(*(const float4*)ap, *(const float4*)(ap + 4));
            }
        }
        const float* bp = &Bw[(size_t)(bn + (tid >> 2)) * K + k0 + (tid & 3) * 8];
        short8 bval = f2b8(*(const float4*)bp, *(const float4*)(bp + 4));

        __syncthreads();
#pragma unroll
        for (int i = 0; i < MF; ++i) {
            int idx = tid + i * 256;
            *(short8*)&As[idx >> 2][(idx & 3) * 8] = aval[i];
        }
        *(short8*)&Bs[tid >> 2][(tid & 3) * 8] = bval;
        __syncthreads();

        short8 af[MF], bf[4];
#pragma unroll
        for (int mi = 0; mi < MF; ++mi)
            af[mi] = *(const short8*)&As[wrow + mi * 16 + frow][fk];
#pragma unroll
        for (int ni = 0; ni < 4; ++ni)
            bf[ni] = *(const short8*)&Bs[ni * 16 + frow][fk];
#pragma unroll
        for (int mi = 0; mi < MF; ++mi)
#pragma unroll
            for (int ni = 0; ni < 4; ++ni)
                acc[mi][ni] = __builtin_amdgcn_mfma_f32_16x16x32_bf16(
                                  af[mi], bf[ni], acc[mi][ni], 0, 0, 0);
    }

#pragma unroll
    for (int mi = 0; mi < MF; ++mi) {
        int rbase = bm + wrow + mi * 16 + orow;
#pragma unroll
        for (int ni = 0; ni < 4; ++ni) {
            int col = bn + ni * 16 + frow;
#pragma unroll
            for (int r = 0; r < 4; ++r) {
                if (CBF)
                    ((ushort*)Cv)[(size_t)(rbase + r) * N + col] = f2b(acc[mi][ni][r]);
                else
                    ((float*)Cv)[(size_t)(rbase + r) * N + col] = acc[mi][ni][r];
            }
        }
    }
}

// ---------------------------------------------------------------------------
// Depthwise 3x3 conv (SAME) + bias + SiLU on bf16 NHWC input; scatter into
// the four scan orders xsb[b][k][l'][d] (bf16).
// ---------------------------------------------------------------------------
__global__ __launch_bounds__(256) void conv_silu_scatter(
        const ushort* __restrict__ xzb, const float* __restrict__ cw,
        const float* __restrict__ cb, ushort* __restrict__ xsb) {
    int idx = blockIdx.x * 256 + threadIdx.x;
    int c = idx % CIN;
    int rest = idx / CIN;
    int w = rest % W_SZ; rest /= W_SZ;
    int h = rest % H_SZ;
    int b = rest / H_SZ;

    float acc = cb[c];
#pragma unroll
    for (int dh = -1; dh <= 1; ++dh) {
        int hh = h + dh;
        if (hh < 0 || hh >= H_SZ) continue;
#pragma unroll
        for (int dw = -1; dw <= 1; ++dw) {
            int ww = w + dw;
            if (ww < 0 || ww >= W_SZ) continue;
            acc += b2f(xzb[(size_t)((b * H_SZ + hh) * W_SZ + ww) * CIN + c])
                 * cw[c * 9 + (dh + 1) * 3 + (dw + 1)];
        }
    }
    float s = acc / (1.f + __expf(-acc));   // SiLU

    int k = c / DI, d = c % DI;
    int lrow = h * W_SZ + w;
    int lcol = w * H_SZ + h;
    int l;
    if      (k == 0) l = lrow;
    else if (k == 1) l = lcol;
    else if (k == 2) l = L_SZ - 1 - lrow;
    else             l = L_SZ - 1 - lcol;
    xsb[(size_t)((b * KG + k) * L_SZ + l) * DI + d] = f2b(s);
}

// ---------------------------------------------------------------------------
// MFMA fused x-projection + dt-projection (768 threads = 12 waves).
// dts emitted as bf16.
// ---------------------------------------------------------------------------
__global__ __launch_bounds__(768) void xproj_dt_mfma(
        const ushort* __restrict__ xsb, const float* __restrict__ xpw,
        const float* __restrict__ dtw, const float* __restrict__ dtb,
        float* __restrict__ xdbl, ushort* __restrict__ dts_b) {
    __shared__ ushort Ws[48][200];
    __shared__ ushort Wd[192][40];
    __shared__ ushort dsh[64][40];

    const int tid  = threadIdx.x;
    const int lane = tid & 63;
    const int wave = tid >> 6;        // 0..11
    const int bm = blockIdx.x * 64;
    const int bk = blockIdx.y;
    const int k  = bk & 3;
    const int frow = lane & 15;
    const int fk   = (lane >> 4) * 8;
    const int orow = (lane >> 4) * 4;
    const int rg = wave & 3;
    const int cg = wave >> 2;

#pragma unroll
    for (int i = 0; i < 3; ++i) {
        int idx = tid + i * 768;
        int row = idx / 48, g = idx % 48;
        ushort4 u = {0, 0, 0, 0};
        if (row < XD) {
            float4 v = *(const float4*)&xpw[((size_t)(k * XD) + row) * 192 + g * 4];
            u.x = f2b(v.x); u.y = f2b(v.y); u.z = f2b(v.z); u.w = f2b(v.w);
        }
        *(ushort4*)&Ws[row][g * 4] = u;
    }
#pragma unroll
    for (int i = 0; i < 2; ++i) {
        int idx = tid + i * 768;
        if (idx < 960) {
            float4 z = {0.f, 0.f, 0.f, 0.f};
            *(float4*)&Wd[idx / 5][(idx % 5) * 8] = z;
        } else if (idx < 1280) {
            int j = idx - 960;
            float4 z = {0.f, 0.f, 0.f, 0.f};
            *(float4*)&dsh[j / 5][(j % 5) * 8] = z;
        }
    }
    __syncthreads();

#pragma unroll
    for (int i = 0; i < 3; ++i) {
        int idx = tid + i * 768;
        int row = idx / RR, c = idx % RR;
        Wd[row][c] = f2b(dtw[((size_t)(k * DI) + row) * RR + c]);
    }

    f32x4 acc1 = {};
    const ushort* arow = &xsb[(size_t)(bk * L_SZ + bm + rg * 16 + frow) * DI];
#pragma unroll
    for (int k0 = 0; k0 < 192; k0 += 32) {
        short8 af = *(const short8*)&arow[k0 + fk];
        short8 bv = *(const short8*)&Ws[cg * 16 + frow][k0 + fk];
        acc1 = __builtin_amdgcn_mfma_f32_16x16x32_bf16(af, bv, acc1, 0, 0, 0);
    }

    {
        int col = cg * 16 + frow;
#pragma unroll
        for (int r = 0; r < 4; ++r) {
            float v = acc1[r];
            int row = rg * 16 + orow + r;
            if (col >= RR && col < XD)
                xdbl[(size_t)(bk * L_SZ + bm + row) * XD + col] = v;
            if (cg == 0 && col < RR)
                dsh[row][col] = f2b(v);
        }
    }
    __syncthreads();

    {
        int d = wave * 16 + frow;
        short8 bv = *(const short8*)&Wd[d][fk];
        float bias = dtb[k * DI + d];
#pragma unroll
        for (int rg2 = 0; rg2 < 4; ++rg2) {
            short8 af2 = *(const short8*)&dsh[rg2 * 16 + frow][fk];
            f32x4 a2 = {};
            a2 = __builtin_amdgcn_mfma_f32_16x16x32_bf16(af2, bv, a2, 0, 0, 0);
#pragma unroll
            for (int r = 0; r < 4; ++r) {
                float a = a2[r] + bias;
                float sp = (a > 20.f) ? a : log1pf(__expf(a));
                dts_b[(size_t)(bk * L_SZ + bm + rg2 * 16 + orow + r) * DI + d] = f2b(sp);
            }
        }
    }
}

// ---------------------------------------------------------------------------
// Scan pass A: per (bk, chunk, d, n) E = prod(e_l), S = local scan. CL=32.
// Fast path (wave-uniform, data-checked): Aa[n] == -(n+1) -> e1-power chain
// (1 exp + 15 muls instead of 16 exps; E via P^(n+1) at the end).
// ---------------------------------------------------------------------------
__global__ __launch_bounds__(192) void scan_passA(
        const ushort* __restrict__ dts_b, const ushort* __restrict__ xsb,
        const float* __restrict__ xdbl, const float* __restrict__ A_logs,
        float* __restrict__ Ebuf, float* __restrict__ Sbuf) {
    int blk = blockIdx.x;
    int bk = blk / NC, ch = blk % NC;
    int d = threadIdx.x, k = bk % KG;
    int l0 = ch * CL;

    __shared__ float bsh[CL][NS];
    for (int t = threadIdx.x; t < CL * NS; t += 192) {
        int l = t / NS, n = t % NS;
        bsh[l][n] = xdbl[(size_t)(bk * L_SZ + l0 + l) * XD + RR + n];
    }
    __syncthreads();

    float Aa[NS], E[NS], S[NS];
    const float* ar = &A_logs[(size_t)(k * DI + d) * NS];
    bool fast = true;
#pragma unroll
    for (int n = 0; n < NS; ++n) {
        Aa[n] = -__expf(ar[n]);
        E[n] = 1.f; S[n] = 0.f;
        fast = fast && (fabsf(Aa[n] + (float)(n + 1)) < 1e-4f * (n + 1));
    }

    if (fast) {
        float P = 1.f;
#pragma unroll 4
        for (int l = 0; l < CL; ++l) {
            float dt = b2f(dts_b[(size_t)(bk * L_SZ + l0 + l) * DI + d]);
            float u  = b2f(xsb [(size_t)(bk * L_SZ + l0 + l) * DI + d]);
            float du = dt * u;
            float4 b0 = *(const float4*)&bsh[l][0];
            float4 b1 = *(const float4*)&bsh[l][4];
            float4 b2 = *(const float4*)&bsh[l][8];
            float4 b3 = *(const float4*)&bsh[l][12];
            float Bv[NS] = {b0.x,b0.y,b0.z,b0.w, b1.x,b1.y,b1.z,b1.w,
                            b2.x,b2.y,b2.z,b2.w, b3.x,b3.y,b3.z,b3.w};
            float e1 = __expf(-dt);
            P *= e1;
            float e = e1;
            S[0] = fmaf(S[0], e, du * Bv[0]);
#pragma unroll
            for (int n = 1; n < NS; ++n) {
                e *= e1;
                S[n] = fmaf(S[n], e, du * Bv[n]);
            }
        }
        E[0] = P;
#pragma unroll
        for (int n = 1; n < NS; ++n) E[n] = E[n - 1] * P;
    } else {
#pragma unroll 4
        for (int l = 0; l < CL; ++l) {
            float dt = b2f(dts_b[(size_t)(bk * L_SZ + l0 + l) * DI + d]);
            float u  = b2f(xsb [(size_t)(bk * L_SZ + l0 + l) * DI + d]);
            float du = dt * u;
            float4 b0 = *(const float4*)&bsh[l][0];
            float4 b1 = *(const float4*)&bsh[l][4];
            float4 b2 = *(const float4*)&bsh[l][8];
            float4 b3 = *(const float4*)&bsh[l][12];
            float Bv[NS] = {b0.x,b0.y,b0.z,b0.w, b1.x,b1.y,b1.z,b1.w,
                            b2.x,b2.y,b2.z,b2.w, b3.x,b3.y,b3.z,b3.w};
#pragma unroll
            for (int n = 0; n < NS; ++n) {
                float e = __expf(dt * Aa[n]);
                E[n] *= e;
                S[n] = fmaf(S[n], e, du * Bv[n]);
            }
        }
    }
    float* ep = &Ebuf[(size_t)((bk * NC + ch) * DI + d) * NS];
    float* sp = &Sbuf[(size_t)((bk * NC + ch) * DI + d) * NS];
#pragma unroll
    for (int n = 0; n < NS; ++n) { ep[n] = E[n]; sp[n] = S[n]; }
}

// ---------------------------------------------------------------------------
// Scan pass B: chunk prefix; one thread per (bk,d,4n) -> float4 chains.
// ---------------------------------------------------------------------------
__global__ __launch_bounds__(256) void scan_passB(
        const float* __restrict__ Ebuf, const float* __restrict__ Sbuf,
        float* __restrict__ Hstart) {
    int t = blockIdx.x * 256 + threadIdx.x;       // 8*192*4 = 6144
    int bk = t / (DI * 4);
    int dn = (t % (DI * 4)) * 4;
    size_t off = (size_t)(bk * NC) * DI * NS + dn;
    const size_t stride = (size_t)DI * NS;

    float4 h = {0.f, 0.f, 0.f, 0.f};
    float4 e = *(const float4*)&Ebuf[off];
    float4 s = *(const float4*)&Sbuf[off];
    for (int c = 0; c < NC; ++c) {
        float4 en = {0.f,0.f,0.f,0.f}, sn = {0.f,0.f,0.f,0.f};
        if (c + 1 < NC) {
            en = *(const float4*)&Ebuf[off + stride];
            sn = *(const float4*)&Sbuf[off + stride];
        }
        *(float4*)&Hstart[off] = h;
        h.x = fmaf(e.x, h.x, s.x);
        h.y = fmaf(e.y, h.y, s.y);
        h.z = fmaf(e.z, h.z, s.z);
        h.w = fmaf(e.w, h.w, s.w);
        off += stride; e = en; s = sn;
    }
}

// ---------------------------------------------------------------------------
// Scan pass C: replay chunk with true h_start, emit y (bf16 spatial scatter).
// Wave-uniform exp fast path.
// ---------------------------------------------------------------------------
__global__ __launch_bounds__(192) void scan_passC(
        const ushort* __restrict__ dts_b, const ushort* __restrict__ xsb,
        const float* __restrict__ xdbl, const float* __restrict__ A_logs,
        const float* __restrict__ Hstart, const float* __restrict__ Ds,
        ushort* __restrict__ ypre_b) {
    int blk = blockIdx.x;
    int bk = blk / NC, ch = blk % NC;
    int d = threadIdx.x, k = bk % KG, b = bk / KG;
    int l0 = ch * CL;

    __shared__ float bsh[CL][NS];
    __shared__ float csh[CL][NS];
    for (int t = threadIdx.x; t < CL * NS; t += 192) {
        int l = t / NS, n = t % NS;
        const float* row = &xdbl[(size_t)(bk * L_SZ + l0 + l) * XD];
        bsh[l][n] = row[RR + n];
        csh[l][n] = row[RR + NS + n];
    }
    __syncthreads();

    float Aa[NS], h[NS];
    const float* ar = &A_logs[(size_t)(k * DI + d) * NS];
    const float* hp = &Hstart[(size_t)((bk * NC + ch) * DI + d) * NS];
    bool fast = true;
#pragma unroll
    for (int n = 0; n < NS; ++n) {
        Aa[n] = -__expf(ar[n]);
        h[n] = hp[n];
        fast = fast && (fabsf(Aa[n] + (float)(n + 1)) < 1e-4f * (n + 1));
    }
    float Dd = Ds[k * DI + d];

#pragma unroll 4
    for (int l = 0; l < CL; ++l) {
        float dt = b2f(dts_b[(size_t)(bk * L_SZ + l0 + l) * DI + d]);
        float u  = b2f(xsb [(size_t)(bk * L_SZ + l0 + l) * DI + d]);
        float du = dt * u;
        float4 b0 = *(const float4*)&bsh[l][0];
        float4 b1 = *(const float4*)&bsh[l][4];
        float4 b2 = *(const float4*)&bsh[l][8];
        float4 b3 = *(const float4*)&bsh[l][12];
        float Bv[NS] = {b0.x,b0.y,b0.z,b0.w, b1.x,b1.y,b1.z,b1.w,
                        b2.x,b2.y,b2.z,b2.w, b3.x,b3.y,b3.z,b3.w};
        float4 c0 = *(const float4*)&csh[l][0];
        float4 c1 = *(const float4*)&csh[l][4];
        float4 c2 = *(const float4*)&csh[l][8];
        float4 c3 = *(const float4*)&csh[l][12];
        float Cv[NS] = {c0.x,c0.y,c0.z,c0.w, c1.x,c1.y,c1.z,c1.w,
                        c2.x,c2.y,c2.z,c2.w, c3.x,c3.y,c3.z,c3.w};
        float p[NS];
        if (fast) {
            float e1 = __expf(-dt);
            float e = e1;
            h[0] = fmaf(h[0], e, du * Bv[0]);
            p[0] = h[0] * Cv[0];
#pragma unroll
            for (int n = 1; n < NS; ++n) {
                e *= e1;
                h[n] = fmaf(h[n], e, du * Bv[n]);
                p[n] = h[n] * Cv[n];
            }
        } else {
#pragma unroll
            for (int n = 0; n < NS; ++n) {
                float e = __expf(dt * Aa[n]);
                h[n] = fmaf(h[n], e, du * Bv[n]);
                p[n] = h[n] * Cv[n];
            }
        }
#pragma unroll
        for (int s = 8; s >= 1; s >>= 1)
#pragma unroll
            for (int n = 0; n < 8; ++n)
                if (n < s) p[n] = p[n] + p[n + s];
        float y = fmaf(Dd, u, p[0]);

        int lg = l0 + l;
        int pos;
        if      (k == 0) pos = lg;
        else if (k == 1) pos = (lg % H_SZ) * W_SZ + (lg / H_SZ);
        else if (k == 2) pos = L_SZ - 1 - lg;
        else { int j = L_SZ - 1 - lg; pos = (j % H_SZ) * W_SZ + (j / H_SZ); }
        ypre_b[(size_t)(b * L_SZ + pos) * CIN + k * DI + d] = f2b(y);
    }
}

// ---------------------------------------------------------------------------
// LayerNorm over CIN=768; bf16 in, bf16 out (stats in fp32).
// ---------------------------------------------------------------------------
__global__ __launch_bounds__(256) void layernorm_bf16(
        const ushort* __restrict__ y, ushort* __restrict__ yb,
        const float* __restrict__ w, const float* __restrict__ bg) {
    int wave = threadIdx.x >> 6, lane = threadIdx.x & 63;
    int tok = blockIdx.x * 4 + wave;
    const ushort* row = &y[(size_t)tok * CIN];
    ushort* rowo = &yb[(size_t)tok * CIN];
    float v[12];
    float s = 0.f;
#pragma unroll
    for (int i = 0; i < 12; ++i) { v[i] = b2f(row[lane + i * 64]); s += v[i]; }
#pragma unroll
    for (int off = 32; off >= 1; off >>= 1) s += __shfl_xor(s, off, 64);
    float mu = s * (1.f / CIN);
    float s2 = 0.f;
#pragma unroll
    for (int i = 0; i < 12; ++i) { float t = v[i] - mu; s2 += t * t; }
#pragma unroll
    for (int off = 32; off >= 1; off >>= 1) s2 += __shfl_xor(s2, off, 64);
    float rstd = rsqrtf(s2 * (1.f / CIN) + 1e-5f);
#pragma unroll
    for (int i = 0; i < 12; ++i)
        rowo[lane + i * 64] =
            f2b((v[i] - mu) * rstd * w[lane + i * 64] + bg[lane + i * 64]);
}

// ---------------------------------------------------------------------------
extern "C" void kernel_launch(void* const* d_in, const int* in_sizes, int n_in,
                              void* d_out, int out_size, void* d_ws, size_t ws_size,
                              hipStream_t stream) {
    const float* x    = (const float*)d_in[0];
    const float* inw  = (const float*)d_in[1];
    const float* cw   = (const float*)d_in[2];
    const float* cb   = (const float*)d_in[3];
    const float* xpw  = (const float*)d_in[4];
    const float* dtw  = (const float*)d_in[5];
    const float* dtb  = (const float*)d_in[6];
    const float* alog = (const float*)d_in[7];
    const float* Dsp  = (const float*)d_in[8];
    const float* lnw  = (const float*)d_in[9];
    const float* lnb  = (const float*)d_in[10];
    const float* outw = (const float*)d_in[11];
    float* out = (float*)d_out;

    float* ws = (float*)d_ws;
    const size_t SZ_BIG = (size_t)MTOK * CIN;            // 3,538,944
    const size_t SCAN_SL = (size_t)8 * NC * DI * NS;     // 1,769,472
    float* xz    = ws;                                   // bf16 in-proj out; later ypre_b
    float* xsbf  = xz  + SZ_BIG;                         // bf16 xs (float slots)
    float* dts   = xsbf + SZ_BIG / 2;                    // bf16 dts; later ynrm_b
    float* xdbl  = dts + SZ_BIG;                         // (8,L,44) fp32
    float* Ebuf  = xdbl + (size_t)8 * L_SZ * XD;
    float* Sbuf  = Ebuf + SCAN_SL;
    float* Hst   = Sbuf + SCAN_SL;
    // overlays (strictly sequential producer/consumer):
    ushort* xzb    = (ushort*)xz;     // gemm1 out (bf16) -> conv in
    ushort* xsb    = (ushort*)xsbf;   // conv -> xproj + scans
    ushort* dtsb   = (ushort*)dts;    // xproj -> scans
    ushort* ypre_b = (ushort*)xz;     // scanC out -> LN in (xzb dead after conv)
    ushort* ynrm_b = (ushort*)dts;    // LN out -> out-proj (dtsb dead after scanC)

    // 1. in-proj GEMM (bf16 MFMA, inline fp32->bf16 A-cast, bf16 C out)
    gemm_tn64<128, false, true><<<dim3(CIN / 64, MTOK / 128), 256, 0, stream>>>(
        x, inw, xzb, MTOK, CIN, 384);
    // 2. depthwise conv + SiLU + scatter (bf16 in/out)
    conv_silu_scatter<<<(B_SZ * H_SZ * W_SZ * CIN) / 256, 256, 0, stream>>>(xzb, cw, cb, xsb);
    // 3. fused MFMA x-projection + dt-projection (bf16 dts out)
    xproj_dt_mfma<<<dim3(L_SZ / 64, 8), 768, 0, stream>>>(xsb, xpw, dtw, dtb, xdbl, dtsb);
    // 4-6. chunked selective scan (CL=32)
    scan_passA<<<8 * NC, 192, 0, stream>>>(dtsb, xsb, xdbl, alog, Ebuf, Sbuf);
    scan_passB<<<(8 * DI * 4) / 256, 256, 0, stream>>>(Ebuf, Sbuf, Hst);
    scan_passC<<<8 * NC, 192, 0, stream>>>(dtsb, xsb, xdbl, alog, Hst, Dsp, ypre_b);
    // 7. LayerNorm: bf16 in, bf16 out
    layernorm_bf16<<<MTOK / 4, 256, 0, stream>>>(ypre_b, ynrm_b, lnw, lnb);
    // 8. out-proj GEMM (bf16 A, inline-cast B, fp32 out)
    gemm_tn64<64, true, false><<<dim3(384 / 64, MTOK / 64), 256, 0, stream>>>(
        ynrm_b, outw, out, MTOK, 384, CIN);
}